// Round 1
// baseline (188.042 us; speedup 1.0000x reference)
//
#include <hip/hip_runtime.h>

#define NSIDE 256
#define HW    65536   // 256*256
#define NB    4       // batch
#define NMAP  8       // 4 pred + 4 gt

struct Hdr {
    double acc;
    int hasFg[NMAP];
};

// ws layout
static const size_t MASK_OFF  = 64;                         // u8  [NMAP][HW]
static const size_t D1_OFF    = MASK_OFF + (size_t)NMAP*HW; // u16 [NMAP][2][NSIDE][NSIDE] (transposed: [x][y])
static const size_t FIELD_OFF = D1_OFF + (size_t)NMAP*2*HW*2; // f32 [NMAP][HW] (row-major [y][x])
// total = 64 + 512KiB + 2MiB + 2MiB ~= 4.5 MiB

__global__ void k_init(Hdr* hdr) {
    if (threadIdx.x == 0) hdr->acc = 0.0;
    if (threadIdx.x < NMAP) hdr->hasFg[threadIdx.x] = 0;
}

// grid: 4*256 blocks of 256 threads. Writes binary masks, ORs per-image has_fg.
__global__ void k_mask(const float* __restrict__ mo, const float* __restrict__ gt,
                       unsigned char* __restrict__ mask, Hdr* __restrict__ hdr) {
    int b = blockIdx.x >> 8;
    int p = ((blockIdx.x & 255) << 8) | threadIdx.x;
    float c0 = mo[(size_t)(b * 2 + 0) * HW + p];
    float c1 = mo[(size_t)(b * 2 + 1) * HW + p];
    int predBit = (c1 > c0) ? 1 : 0;                 // argmax, first-max tie -> 0
    int gtBit   = (gt[(size_t)b * HW + p] > 0.5f) ? 1 : 0;
    mask[(size_t)b * HW + p]        = (unsigned char)predBit;
    mask[(size_t)(NB + b) * HW + p] = (unsigned char)gtBit;
    unsigned long long bp = __ballot(predBit);
    unsigned long long bg = __ballot(gtBit);
    if ((threadIdx.x & 63) == 0) {
        if (bp) atomicOr(&hdr->hasFg[b], 1);
        if (bg) atomicOr(&hdr->hasFg[NB + b], 1);
    }
}

// nearest set bit distance in a 256-bit LDS bitset; returns big value if none
__device__ __forceinline__ int nearest_bit(const unsigned long long* z, int x) {
    int xw = x >> 6, xb = x & 63;
    int best = 1 << 20;
    // left: highest set bit at pos <= x
    unsigned long long w = z[xw] & ((2ull << xb) - 1ull);   // bits 0..xb (xb=63 -> all ones)
    if (w) {
        best = x - ((xw << 6) + 63 - __clzll(w));
    } else {
        for (int k = xw - 1; k >= 0; --k) {
            if (z[k]) { best = x - ((k << 6) + 63 - __clzll(z[k])); break; }
        }
    }
    // right: lowest set bit at pos >= x
    unsigned long long w2 = z[xw] & (~0ull << xb);
    if (w2) {
        int r = (xw << 6) + __builtin_ctzll(w2);
        int d = r - x;
        if (d < best) best = d;
    } else {
        for (int k = xw + 1; k < 4; ++k) {
            if (z[k]) {
                int r = (k << 6) + __builtin_ctzll(z[k]);
                int d = r - x;
                if (d < best) best = d;
                break;
            }
        }
    }
    return best;
}

// Pass 1 (along W): grid 8*256 blocks (one per (map,row)), 256 threads (one per x).
// Result for a binary row is (dist to nearest zero)^2, or sentinel 0xFFFF meaning 1e9.
// Written transposed: d1t[m][sense][x][y] so pass 2 reads columns contiguously.
__global__ void k_row(const unsigned char* __restrict__ mask, unsigned short* __restrict__ d1t) {
    int m = blockIdx.x >> 8;
    int y = blockIdx.x & 255;
    int x = threadIdx.x;
    int mb = mask[(size_t)m * HW + y * NSIDE + x];
    __shared__ unsigned long long zF[4], zB[4];
    unsigned long long balF = __ballot(mb == 0);   // zeros of fg-mask (bg pixels)
    unsigned long long balB = __ballot(mb != 0);   // zeros of bg-mask (fg pixels)
    if ((threadIdx.x & 63) == 0) {
        zF[threadIdx.x >> 6] = balF;
        zB[threadIdx.x >> 6] = balB;
    }
    __syncthreads();
    int dF = nearest_bit(zF, x);
    int dB = nearest_bit(zB, x);
    unsigned short vF = (dF > 255) ? (unsigned short)0xFFFFu : (unsigned short)(dF * dF);
    unsigned short vB = (dB > 255) ? (unsigned short)0xFFFFu : (unsigned short)(dB * dB);
    size_t base = (size_t)m * 2 * HW;
    d1t[base + (size_t)x * NSIDE + y]      = vF;
    d1t[base + HW + (size_t)x * NSIDE + y] = vB;
}

// Pass 2 (along H): grid 8*256 blocks (one per (map,column)), 256 threads (one per y).
// Brute-force min_j d1[j] + (y-j)^2 in fp32 — identical arithmetic to the reference.
__global__ void k_col(const unsigned short* __restrict__ d1t, float* __restrict__ field) {
    int m = blockIdx.x >> 8;
    int x = blockIdx.x & 255;
    int y = threadIdx.x;
    __shared__ float cf[NSIDE], cb[NSIDE];
    size_t base = (size_t)m * 2 * HW + (size_t)x * NSIDE;
    unsigned short vF = d1t[base + y];
    unsigned short vB = d1t[base + HW + y];
    cf[y] = (vF == 0xFFFFu) ? 1e9f : (float)vF;
    cb[y] = (vB == 0xFFFFu) ? 1e9f : (float)vB;
    __syncthreads();
    float bf = 3e9f, bb = 3e9f;
    float fy = (float)y;
#pragma unroll 8
    for (int j = 0; j < NSIDE; ++j) {
        float d  = fy - (float)j;
        float dd = d * d;
        bf = fminf(bf, cf[j] + dd);
        bb = fminf(bb, cb[j] + dd);
    }
    // field^2 at a pixel: exactly one of (fg,bg) sqEDT is nonzero -> sum equals (sqrt(a)+sqrt(b))^2
    field[(size_t)m * HW + (size_t)y * NSIDE + x] = bf + bb;
}

// Final reduce: err * dist with per-image has_fg guard; double atomic accumulate.
__global__ void k_reduce(const unsigned char* __restrict__ mask,
                         const float* __restrict__ field,
                         Hdr* __restrict__ hdr) {
    int p = blockIdx.x * 256 + threadIdx.x;
    float s = 0.0f;
#pragma unroll
    for (int b = 0; b < NB; ++b) {
        int mp = mask[(size_t)b * HW + p];
        int mg = mask[(size_t)(NB + b) * HW + p];
        if (mp != mg) {
            float fP = hdr->hasFg[b]      ? field[(size_t)b * HW + p]        : 0.0f;
            float fG = hdr->hasFg[NB + b] ? field[(size_t)(NB + b) * HW + p] : 0.0f;
            s += fP + fG;
        }
    }
#pragma unroll
    for (int off = 32; off > 0; off >>= 1) s += __shfl_down(s, off, 64);
    __shared__ float part[4];
    if ((threadIdx.x & 63) == 0) part[threadIdx.x >> 6] = s;
    __syncthreads();
    if (threadIdx.x == 0) {
        float t = part[0] + part[1] + part[2] + part[3];
        atomicAdd(&hdr->acc, (double)t);
    }
}

__global__ void k_final(const Hdr* __restrict__ hdr, float* __restrict__ out) {
    if (threadIdx.x == 0) out[0] = (float)(hdr->acc * (1.0 / (double)(NB * HW)));
}

extern "C" void kernel_launch(void* const* d_in, const int* in_sizes, int n_in,
                              void* d_out, int out_size, void* d_ws, size_t ws_size,
                              hipStream_t stream) {
    const float* mo = (const float*)d_in[0];
    const float* gt = (const float*)d_in[1];
    float* out = (float*)d_out;
    char* ws = (char*)d_ws;

    Hdr* hdr            = (Hdr*)ws;
    unsigned char* mask = (unsigned char*)(ws + MASK_OFF);
    unsigned short* d1t = (unsigned short*)(ws + D1_OFF);
    float* field        = (float*)(ws + FIELD_OFF);

    hipLaunchKernelGGL(k_init,   dim3(1),        dim3(64),  0, stream, hdr);
    hipLaunchKernelGGL(k_mask,   dim3(NB * 256), dim3(256), 0, stream, mo, gt, mask, hdr);
    hipLaunchKernelGGL(k_row,    dim3(NMAP * 256), dim3(256), 0, stream, mask, d1t);
    hipLaunchKernelGGL(k_col,    dim3(NMAP * 256), dim3(256), 0, stream, d1t, field);
    hipLaunchKernelGGL(k_reduce, dim3(256),      dim3(256), 0, stream, mask, field, hdr);
    hipLaunchKernelGGL(k_final,  dim3(1),        dim3(64),  0, stream, hdr, out);
}

// Round 2
// 84.639 us; speedup vs baseline: 2.2217x; 2.2217x over previous
//
#include <hip/hip_runtime.h>

#define NSIDE 256
#define HW    65536   // 256*256
#define NB    4       // batch
#define NMAP  8       // 4 pred + 4 gt

// ws layout (all regions written before read within one launch sequence)
static const size_t MASK_OFF  = 0;                               // u8  [NMAP][HW] row-major
static const size_t D1_OFF    = MASK_OFF + (size_t)NMAP * HW;    // u16 [NMAP][2][NSIDE][NSIDE] transposed [x][y]
static const size_t ROWFG_OFF = D1_OFF + (size_t)NMAP * 2 * HW * 2; // u8 [NMAP][NSIDE] per-row has-fg flag
static const size_t PART_OFF  = ROWFG_OFF + (size_t)NMAP * NSIDE;   // f32 [NMAP][NSIDE] per-column partial sums
// total ~2.6 MiB

// nearest set bit distance in a 256-bit LDS bitset; returns big value if none
__device__ __forceinline__ int nearest_bit(const unsigned long long* z, int x) {
    int xw = x >> 6, xb = x & 63;
    int best = 1 << 20;
    // left: highest set bit at pos <= x
    unsigned long long w = z[xw] & ((2ull << xb) - 1ull);
    if (w) {
        best = x - ((xw << 6) + 63 - __clzll(w));
    } else {
        for (int k = xw - 1; k >= 0; --k) {
            if (z[k]) { best = x - ((k << 6) + 63 - __clzll(z[k])); break; }
        }
    }
    // right: lowest set bit at pos >= x
    unsigned long long w2 = z[xw] & (~0ull << xb);
    if (w2) {
        int r = (xw << 6) + __builtin_ctzll(w2);
        int d = r - x;
        if (d < best) best = d;
    } else {
        for (int k = xw + 1; k < 4; ++k) {
            if (z[k]) {
                int r = (k << 6) + __builtin_ctzll(z[k]);
                int d = r - x;
                if (d < best) best = d;
                break;
            }
        }
    }
    return best;
}

// Fused mask + row-DT (pass 1 along W).
// grid: NMAP*256 blocks (one per (map,row)), 256 threads (one per x).
// Row DT of a binary row = (dist to nearest zero bit)^2, sentinel 0xFFFF == 1e9.
// No atomics: per-row fg flag written as one byte per block.
__global__ void k_rowmask(const float* __restrict__ mo, const float* __restrict__ gt,
                          unsigned char* __restrict__ mask, unsigned short* __restrict__ d1t,
                          unsigned char* __restrict__ rowFg) {
    int m = blockIdx.x >> 8;
    int y = blockIdx.x & 255;
    int x = threadIdx.x;
    int bit;
    if (m < NB) {   // pred map: argmax over 2 channels, first-max tie -> 0
        float c0 = mo[(size_t)(m * 2 + 0) * HW + y * NSIDE + x];
        float c1 = mo[(size_t)(m * 2 + 1) * HW + y * NSIDE + x];
        bit = (c1 > c0) ? 1 : 0;
    } else {        // gt map
        bit = (gt[(size_t)(m - NB) * HW + y * NSIDE + x] > 0.5f) ? 1 : 0;
    }
    mask[(size_t)m * HW + y * NSIDE + x] = (unsigned char)bit;

    __shared__ unsigned long long zF[4], zB[4];
    unsigned long long balF = __ballot(bit == 0);   // zeros of fg-mask
    unsigned long long balB = __ballot(bit != 0);   // zeros of bg-mask (= fg pixels)
    if ((threadIdx.x & 63) == 0) {
        zF[threadIdx.x >> 6] = balF;
        zB[threadIdx.x >> 6] = balB;
    }
    __syncthreads();
    int dF = nearest_bit(zF, x);
    int dB = nearest_bit(zB, x);
    unsigned short vF = (dF > 255) ? (unsigned short)0xFFFFu : (unsigned short)(dF * dF);
    unsigned short vB = (dB > 255) ? (unsigned short)0xFFFFu : (unsigned short)(dB * dB);
    size_t base = (size_t)m * 2 * HW;
    d1t[base + (size_t)x * NSIDE + y]      = vF;   // transposed for pass 2
    d1t[base + HW + (size_t)x * NSIDE + y] = vB;
    if (threadIdx.x == 0)
        rowFg[m * NSIDE + y] = ((zB[0] | zB[1] | zB[2] | zB[3]) != 0ull) ? 1 : 0;
}

// Fused column-DT (pass 2 along H) + err-weighted partial sum.
// grid: NB*256 blocks (one per (image, column)), 256 threads (one per y).
// Computes all 4 DT planes (pred-fg, pred-bg, gt-fg, gt-bg) for the column,
// applies err = (pred != gt), block-reduces per-map partials. fp32 min-conv
// identical to the reference arithmetic.
__global__ void k_colreduce(const unsigned short* __restrict__ d1t,
                            const unsigned char* __restrict__ mask,
                            float* __restrict__ part) {
    int b = blockIdx.x >> 8;
    int x = blockIdx.x & 255;
    int y = threadIdx.x;
    __shared__ float cPf[NSIDE], cPb[NSIDE], cGf[NSIDE], cGb[NSIDE];
    size_t basP = (size_t)b * 2 * HW + (size_t)x * NSIDE;
    size_t basG = (size_t)(NB + b) * 2 * HW + (size_t)x * NSIDE;
    unsigned short vPf = d1t[basP + y];
    unsigned short vPb = d1t[basP + HW + y];
    unsigned short vGf = d1t[basG + y];
    unsigned short vGb = d1t[basG + HW + y];
    cPf[y] = (vPf == 0xFFFFu) ? 1e9f : (float)vPf;
    cPb[y] = (vPb == 0xFFFFu) ? 1e9f : (float)vPb;
    cGf[y] = (vGf == 0xFFFFu) ? 1e9f : (float)vGf;
    cGb[y] = (vGb == 0xFFFFu) ? 1e9f : (float)vGb;
    __syncthreads();
    float bPf = 3e9f, bPb = 3e9f, bGf = 3e9f, bGb = 3e9f;
    float fy = (float)y;
#pragma unroll 8
    for (int j = 0; j < NSIDE; ++j) {
        float d  = fy - (float)j;
        float dd = d * d;
        bPf = fminf(bPf, cPf[j] + dd);
        bPb = fminf(bPb, cPb[j] + dd);
        bGf = fminf(bGf, cGf[j] + dd);
        bGb = fminf(bGb, cGb[j] + dd);
    }
    // err at pixel (y,x): pred != gt (mask column reads hit L2, post-loop)
    int mp = mask[(size_t)b * HW + (size_t)y * NSIDE + x];
    int mg = mask[(size_t)(NB + b) * HW + (size_t)y * NSIDE + x];
    float e = (mp != mg) ? 1.0f : 0.0f;
    float sP = e * (bPf + bPb);   // pred_dt^2 (one sqEDT is exactly 0 at any pixel)
    float sG = e * (bGf + bGb);   // gt_dt^2
#pragma unroll
    for (int off = 32; off > 0; off >>= 1) {
        sP += __shfl_down(sP, off, 64);
        sG += __shfl_down(sG, off, 64);
    }
    __shared__ float rP[4], rG[4];
    int wid = threadIdx.x >> 6;
    if ((threadIdx.x & 63) == 0) { rP[wid] = sP; rG[wid] = sG; }
    __syncthreads();
    if (threadIdx.x == 0) {
        part[b * NSIDE + x]        = rP[0] + rP[1] + rP[2] + rP[3];
        part[(NB + b) * NSIDE + x] = rG[0] + rG[1] + rG[2] + rG[3];
    }
}

// Final: OR per-row fg flags -> per-map guard; sum per-column partials; mean.
// 1 block, 256 threads.
__global__ void k_final(const unsigned char* __restrict__ rowFg,
                        const float* __restrict__ part,
                        float* __restrict__ out) {
    int tid = threadIdx.x;
    __shared__ int hasFg[NMAP];
    if (tid < NMAP) hasFg[tid] = 0;
    __syncthreads();
    // rowFg is NMAP*256 = 2048 bytes; each thread ORs one u64 (map = tid>>5)
    const unsigned long long* rf = (const unsigned long long*)rowFg;
    unsigned long long v = rf[tid];
    if (v) atomicOr(&hasFg[tid >> 5], 1);   // LDS atomic, uncontended
    __syncthreads();
    __shared__ float red[4];
    __shared__ double tot_s;
    if (tid == 0) tot_s = 0.0;
    int wid = tid >> 6;
    for (int m = 0; m < NMAP; ++m) {
        float s = part[m * NSIDE + tid];
#pragma unroll
        for (int off = 32; off > 0; off >>= 1) s += __shfl_down(s, off, 64);
        __syncthreads();
        if ((tid & 63) == 0) red[wid] = s;
        __syncthreads();
        if (tid == 0 && hasFg[m]) tot_s += (double)(red[0] + red[1] + red[2] + red[3]);
        __syncthreads();
    }
    if (tid == 0) out[0] = (float)(tot_s * (1.0 / (double)(NB * HW)));
}

extern "C" void kernel_launch(void* const* d_in, const int* in_sizes, int n_in,
                              void* d_out, int out_size, void* d_ws, size_t ws_size,
                              hipStream_t stream) {
    const float* mo = (const float*)d_in[0];
    const float* gt = (const float*)d_in[1];
    float* out = (float*)d_out;
    char* ws = (char*)d_ws;

    unsigned char* mask  = (unsigned char*)(ws + MASK_OFF);
    unsigned short* d1t  = (unsigned short*)(ws + D1_OFF);
    unsigned char* rowFg = (unsigned char*)(ws + ROWFG_OFF);
    float* part          = (float*)(ws + PART_OFF);

    hipLaunchKernelGGL(k_rowmask,   dim3(NMAP * 256), dim3(256), 0, stream, mo, gt, mask, d1t, rowFg);
    hipLaunchKernelGGL(k_colreduce, dim3(NB * 256),   dim3(256), 0, stream, d1t, mask, part);
    hipLaunchKernelGGL(k_final,     dim3(1),          dim3(256), 0, stream, rowFg, part, out);
}

// Round 4
// 66.352 us; speedup vs baseline: 2.8340x; 1.2756x over previous
//
#include <hip/hip_runtime.h>

#define NSIDE 256
#define HW    65536   // 256*256
#define NB    4       // batch
#define NMAP  8       // 4 pred + 4 gt

// ws layout
// d1p: u32 [NMAP][NSIDE(x)][NSIDE(y)] — packed row-DT, lo16 = fg-sense, hi16 = bg-sense,
//      transposed (x-major) so pass-2 reads columns coalesced. 0xFFFF == 1e9 sentinel.
static const size_t D1_OFF    = 0;
static const size_t ROWFG_OFF = (size_t)NMAP * HW * 4;            // u8 [NMAP][NSIDE]
static const size_t PART_OFF  = ROWFG_OFF + (size_t)NMAP * NSIDE; // f32 [NMAP][NSIDE]

// nearest set bit distance in a 256-bit LDS bitset; returns big value if none
__device__ __forceinline__ int nearest_bit(const unsigned long long* z, int x) {
    int xw = x >> 6, xb = x & 63;
    int best = 1 << 20;
    unsigned long long w = z[xw] & ((2ull << xb) - 1ull);   // bits 0..xb
    if (w) {
        best = x - ((xw << 6) + 63 - __clzll(w));
    } else {
        for (int k = xw - 1; k >= 0; --k) {
            if (z[k]) { best = x - ((k << 6) + 63 - __clzll(z[k])); break; }
        }
    }
    unsigned long long w2 = z[xw] & (~0ull << xb);           // bits xb..63
    if (w2) {
        int r = (xw << 6) + __builtin_ctzll(w2);
        if (r - x < best) best = r - x;
    } else {
        for (int k = xw + 1; k < 4; ++k) {
            if (z[k]) {
                int r = (k << 6) + __builtin_ctzll(z[k]);
                if (r - x < best) best = r - x;
                break;
            }
        }
    }
    return best;
}

// Fused mask + row-DT (pass 1 along W). grid: NMAP*256 blocks (one per (map,row)).
// No mask array: pred/gt bit is recoverable in pass 2 from (vF != 0).
__global__ void k_rowmask(const float* __restrict__ mo, const float* __restrict__ gt,
                          unsigned int* __restrict__ d1p, unsigned char* __restrict__ rowFg) {
    int m = blockIdx.x >> 8;
    int y = blockIdx.x & 255;
    int x = threadIdx.x;
    int bit;
    if (m < NB) {   // pred: argmax over 2 channels, first-max tie -> 0
        float c0 = mo[(size_t)(m * 2 + 0) * HW + y * NSIDE + x];
        float c1 = mo[(size_t)(m * 2 + 1) * HW + y * NSIDE + x];
        bit = (c1 > c0) ? 1 : 0;
    } else {
        bit = (gt[(size_t)(m - NB) * HW + y * NSIDE + x] > 0.5f) ? 1 : 0;
    }
    __shared__ unsigned long long zF[4], zB[4];
    unsigned long long balF = __ballot(bit == 0);   // zeros of fg-mask
    unsigned long long balB = __ballot(bit != 0);   // zeros of bg-mask (= fg pixels)
    if ((threadIdx.x & 63) == 0) {
        zF[threadIdx.x >> 6] = balF;
        zB[threadIdx.x >> 6] = balB;
    }
    __syncthreads();
    int dF = nearest_bit(zF, x);
    int dB = nearest_bit(zB, x);
    unsigned int vF = (dF > 255) ? 0xFFFFu : (unsigned int)(dF * dF);
    unsigned int vB = (dB > 255) ? 0xFFFFu : (unsigned int)(dB * dB);
    d1p[((size_t)m * NSIDE + x) * NSIDE + y] = vF | (vB << 16);   // transposed, packed
    if (threadIdx.x == 0)
        rowFg[m * NSIDE + y] = ((zB[0] | zB[1] | zB[2] | zB[3]) != 0ull) ? 1 : 0;
}

// Pass 2 (along H) + err-weighted partial sums, with outward early-exit scan.
// grid: NB*256 blocks (one per (image, column)), 256 threads (one per y).
// Exact: same fp32 min terms as the reference brute force, scanned outward from
// j=y. A plane's min cannot improve once r^2 >= that plane's current best
// (c[j] >= 0), so the wave may stop when r^2 >= MAX over all live planes.
// Lanes with err==0 contribute 0 regardless -> their bests are zeroed so they
// never hold the wave back.
__global__ void k_colreduce(const unsigned int* __restrict__ d1p,
                            float* __restrict__ part) {
    int b = blockIdx.x >> 8;
    int x = blockIdx.x & 255;
    int y = threadIdx.x;
    __shared__ float cPf[NSIDE], cPb[NSIDE], cGf[NSIDE], cGb[NSIDE];
    unsigned int P = d1p[((size_t)b * NSIDE + x) * NSIDE + y];
    unsigned int G = d1p[((size_t)(NB + b) * NSIDE + x) * NSIDE + y];
    unsigned int pf = P & 0xFFFFu, pb = P >> 16;
    unsigned int gf = G & 0xFFFFu, gb = G >> 16;
    cPf[y] = (pf == 0xFFFFu) ? 1e9f : (float)pf;
    cPb[y] = (pb == 0xFFFFu) ? 1e9f : (float)pb;
    cGf[y] = (gf == 0xFFFFu) ? 1e9f : (float)gf;
    cGb[y] = (gb == 0xFFFFu) ? 1e9f : (float)gb;
    __syncthreads();
    // err: fg-sense row-DT is 0 iff pixel is bg -> predBit = (pf != 0)
    float e = ((pf != 0u) != (gf != 0u)) ? 1.0f : 0.0f;
    float bPf = cPf[y], bPb = cPb[y], bGf = cGf[y], bGb = cGb[y];
    if (e == 0.0f) { bPf = 0.0f; bPb = 0.0f; bGf = 0.0f; bGb = 0.0f; }
    float fr = 0.0f;
    for (int r = 1; r < NSIDE; ++r) {
        fr += 1.0f;
        float drr = fr * fr;
        float bmax = fmaxf(fmaxf(bPf, bPb), fmaxf(bGf, bGb));   // MAX: all planes settled
        if (__all(drr >= bmax)) break;
        int jm = y - r, jp = y + r;
        int jmc = jm < 0 ? 0 : jm;
        int jpc = jp > (NSIDE - 1) ? (NSIDE - 1) : jp;
        float aPf = cPf[jmc], aPb = cPb[jmc], aGf = cGf[jmc], aGb = cGb[jmc];
        float qPf = cPf[jpc], qPb = cPb[jpc], qGf = cGf[jpc], qGb = cGb[jpc];
        if (jm < 0) { aPf = 3e9f; aPb = 3e9f; aGf = 3e9f; aGb = 3e9f; }
        if (jp > NSIDE - 1) { qPf = 3e9f; qPb = 3e9f; qGf = 3e9f; qGb = 3e9f; }
        bPf = fminf(bPf, fminf(aPf, qPf) + drr);
        bPb = fminf(bPb, fminf(aPb, qPb) + drr);
        bGf = fminf(bGf, fminf(aGf, qGf) + drr);
        bGb = fminf(bGb, fminf(aGb, qGb) + drr);
    }
    float sP = e * (bPf + bPb);   // pred_dt^2 (one sqEDT is exactly 0 per pixel)
    float sG = e * (bGf + bGb);   // gt_dt^2
#pragma unroll
    for (int off = 32; off > 0; off >>= 1) {
        sP += __shfl_down(sP, off, 64);
        sG += __shfl_down(sG, off, 64);
    }
    __shared__ float rP[4], rG[4];
    int wid = threadIdx.x >> 6;
    if ((threadIdx.x & 63) == 0) { rP[wid] = sP; rG[wid] = sG; }
    __syncthreads();
    if (threadIdx.x == 0) {
        part[b * NSIDE + x]        = rP[0] + rP[1] + rP[2] + rP[3];
        part[(NB + b) * NSIDE + x] = rG[0] + rG[1] + rG[2] + rG[3];
    }
}

// Final: per-map has-fg guard + deterministic sum. 1 block, 256 threads (4 waves).
__global__ void k_final(const unsigned char* __restrict__ rowFg,
                        const float* __restrict__ part,
                        float* __restrict__ out) {
    int tid = threadIdx.x;
    int lane = tid & 63, w = tid >> 6;
    __shared__ int hasFg[NMAP];
    __shared__ float red[NMAP];
    if (tid < NMAP) hasFg[tid] = 0;
    __syncthreads();
    unsigned long long v = ((const unsigned long long*)rowFg)[tid];  // 256 u64 = 2048 B
    if (v) atomicOr(&hasFg[tid >> 5], 1);   // LDS atomic, map = tid>>5
    // each wave reduces two maps via float4 loads
#pragma unroll
    for (int k = 0; k < 2; ++k) {
        int m = 2 * w + k;
        float4 f = ((const float4*)part)[m * 64 + lane];
        float s = f.x + f.y + f.z + f.w;
#pragma unroll
        for (int off = 32; off > 0; off >>= 1) s += __shfl_down(s, off, 64);
        if (lane == 0) red[m] = s;
    }
    __syncthreads();
    if (tid == 0) {
        double t = 0.0;
#pragma unroll
        for (int m = 0; m < NMAP; ++m)
            if (hasFg[m]) t += (double)red[m];
        out[0] = (float)(t * (1.0 / (double)(NB * HW)));
    }
}

extern "C" void kernel_launch(void* const* d_in, const int* in_sizes, int n_in,
                              void* d_out, int out_size, void* d_ws, size_t ws_size,
                              hipStream_t stream) {
    const float* mo = (const float*)d_in[0];
    const float* gt = (const float*)d_in[1];
    float* out = (float*)d_out;
    char* ws = (char*)d_ws;

    unsigned int* d1p    = (unsigned int*)(ws + D1_OFF);
    unsigned char* rowFg = (unsigned char*)(ws + ROWFG_OFF);
    float* part          = (float*)(ws + PART_OFF);

    hipLaunchKernelGGL(k_rowmask,   dim3(NMAP * 256), dim3(256), 0, stream, mo, gt, d1p, rowFg);
    hipLaunchKernelGGL(k_colreduce, dim3(NB * 256),   dim3(256), 0, stream, d1p, part);
    hipLaunchKernelGGL(k_final,     dim3(1),          dim3(256), 0, stream, rowFg, part, out);
}